// Round 1
// baseline (2455.946 us; speedup 1.0000x reference)
//
#include <hip/hip_runtime.h>
#include <hip/hip_bf16.h>

// LightweightMambaCodec: B=16 L=512 DIN=64 DM=256 DI=512 NL=2 LAT=128 N=16 K=4 R=16
// f32 baseline: tiled VALU GEMM + fused conv/silu + fused softplus + fused scan epilogue.

#define DEVINL __device__ __forceinline__

constexpr int MROWS = 16 * 512; // 8192

DEVINL float silu_f(float x) { return x / (1.f + __expf(-x)); }
DEVINL float softplus_f(float x) { return (x > 20.f) ? x : log1pf(__expf(x)); }

// C[M,N] = A[M,K] @ W[N,K]^T (+bias) (+act). A has row stride lda. W row-major NxK.
// ACT: 0 = none, 1 = softplus.
template<int ACT, bool BIAS>
__global__ __launch_bounds__(256) void gemm_f32(
    const float* __restrict__ A, int lda,
    const float* __restrict__ W,
    const float* __restrict__ bias,
    float* __restrict__ C,
    int M, int N, int K)
{
  constexpr int BM = 64, BN = 64, BK = 32;
  __shared__ float As[BK][BM + 4]; // transposed: As[k][m]; stride 68 floats keeps 16B alignment
  __shared__ float Ws[BK][BN + 4];
  const int tid = threadIdx.x;
  const int bn0 = blockIdx.x * BN;
  const int bm0 = blockIdx.y * BM;
  const int tx = tid & 15;       // n-dir
  const int ty = tid >> 4;       // m-dir
  const int ar = tid >> 3;       // 0..31 staging row
  const int ac = (tid & 7) << 2; // 0..28 staging col (float4)

  float acc[4][4] = {};
  for (int k0 = 0; k0 < K; k0 += BK) {
    #pragma unroll
    for (int rr = 0; rr < 2; rr++) {
      int r = ar + rr * 32;
      float4 v = make_float4(0.f, 0.f, 0.f, 0.f);
      if ((k0 + ac < K) && (bm0 + r < M))
        v = *(const float4*)(A + (size_t)(bm0 + r) * lda + k0 + ac);
      As[ac + 0][r] = v.x; As[ac + 1][r] = v.y; As[ac + 2][r] = v.z; As[ac + 3][r] = v.w;
      float4 w = make_float4(0.f, 0.f, 0.f, 0.f);
      if ((k0 + ac < K) && (bn0 + r < N))
        w = *(const float4*)(W + (size_t)(bn0 + r) * K + k0 + ac);
      Ws[ac + 0][r] = w.x; Ws[ac + 1][r] = w.y; Ws[ac + 2][r] = w.z; Ws[ac + 3][r] = w.w;
    }
    __syncthreads();
    #pragma unroll
    for (int kk = 0; kk < BK; kk++) {
      float4 a4 = *(const float4*)&As[kk][ty << 2];
      float4 b4 = *(const float4*)&Ws[kk][tx << 2];
      float av[4] = {a4.x, a4.y, a4.z, a4.w};
      float bv[4] = {b4.x, b4.y, b4.z, b4.w};
      #pragma unroll
      for (int i = 0; i < 4; i++)
        #pragma unroll
        for (int j = 0; j < 4; j++)
          acc[i][j] += av[i] * bv[j];
    }
    __syncthreads();
  }
  #pragma unroll
  for (int i = 0; i < 4; i++) {
    int r = bm0 + (ty << 2) + i;
    int c = bn0 + (tx << 2);
    if (r < M && c < N) { // N always %4==0 here, so float4 guard == scalar guard
      float4 o;
      float* po = &o.x;
      #pragma unroll
      for (int j = 0; j < 4; j++) {
        float v = acc[i][j];
        if (BIAS) v += bias[c + j];
        if (ACT == 1) v = softplus_f(v);
        po[j] = v;
      }
      *(float4*)(C + (size_t)r * N + c) = o;
    }
  }
}

// depthwise causal conv K=4 over (B,L,DI) stored in xz cols [0,512), + bias + silu
__global__ __launch_bounds__(256) void conv_silu_kernel(
    const float* __restrict__ xz,    // (B,L,1024)
    const float* __restrict__ convw, // (512,4)
    const float* __restrict__ convb, // (512)
    float* __restrict__ xc)          // (B,L,512)
{
  int idx = blockIdx.x * 256 + threadIdx.x; // over 16*512*512
  int d = idx & 511;
  int l = (idx >> 9) & 511;
  int b = idx >> 18;
  float acc = convb[d];
  #pragma unroll
  for (int k = 0; k < 4; k++) {
    int ll = l - 3 + k;
    if (ll >= 0) acc += convw[d * 4 + k] * xz[((size_t)(b * 512 + ll)) * 1024 + d];
  }
  xc[idx] = silu_f(acc);
}

// selective scan, fused with +xc*Dp and *silu(z). One 16-lane group per (b,d), lane = n.
__global__ __launch_bounds__(256) void scan_kernel(
    const float* __restrict__ xc,   // u (B,L,512)
    const float* __restrict__ dtb,  // (B,L,512)
    const float* __restrict__ dbl,  // (B,L,48): B at col 16, C at col 32
    const float* __restrict__ xz,   // z at col 512 of (B,L,1024)
    const float* __restrict__ Alog, // (512,16)
    const float* __restrict__ Dp,   // (512)
    float* __restrict__ y)          // (B,L,512)
{
  int tid = threadIdx.x;
  int n = tid & 15;
  int g = tid >> 4;
  int pair = blockIdx.x * 16 + g; // (b,d)
  int b = pair >> 9;
  int d = pair & 511;
  float A_dn = -__expf(Alog[d * 16 + n]);
  float Dv = Dp[d];
  float h = 0.f;
  const float* dt_p = dtb + (size_t)b * 512 * 512 + d;
  const float* u_p  = xc  + (size_t)b * 512 * 512 + d;
  const float* bc_p = dbl + (size_t)b * 512 * 48;
  const float* z_p  = xz  + (size_t)b * 512 * 1024 + 512 + d;
  float* y_p = y + (size_t)b * 512 * 512 + d;
  for (int t = 0; t < 512; t++) {
    float dtv = dt_p[(size_t)t * 512];
    float uv  = u_p[(size_t)t * 512];
    float Bv  = bc_p[t * 48 + 16 + n];
    float Cv  = bc_p[t * 48 + 32 + n];
    h = __expf(dtv * A_dn) * h + (dtv * uv) * Bv;
    float contrib = h * Cv;
    contrib += __shfl_xor(contrib, 1);
    contrib += __shfl_xor(contrib, 2);
    contrib += __shfl_xor(contrib, 4);
    contrib += __shfl_xor(contrib, 8);
    if (n == 0) {
      float zv = z_p[(size_t)t * 1024];
      float yv = contrib + uv * Dv;
      y_p[(size_t)t * 512] = yv * silu_f(zv);
    }
  }
}

__global__ void pool_kernel(const float* __restrict__ h, float* __restrict__ pooled) {
  int b = blockIdx.x, d = threadIdx.x; // 16 blocks x 256
  float s = 0.f;
  for (int l = 0; l < 512; l++) s += h[((size_t)(b * 512 + l)) * 256 + d];
  pooled[b * 256 + d] = s * (1.f / 512.f);
}

__global__ void small_gemm_kernel(const float* __restrict__ A, const float* __restrict__ W,
                                  const float* __restrict__ bias, float* __restrict__ C,
                                  int Mb, int N, int K) {
  int idx = blockIdx.x * blockDim.x + threadIdx.x;
  if (idx >= Mb * N) return;
  int b = idx / N, n = idx - b * N;
  float acc = bias[n];
  for (int k = 0; k < K; k++) acc += A[b * K + k] * W[n * K + k];
  C[idx] = acc;
}

__global__ void bcast_kernel(const float* __restrict__ s, float* __restrict__ h) {
  int idx = blockIdx.x * 256 + threadIdx.x; // over 8192*256
  int d = idx & 255;
  int b = idx >> 17;
  h[idx] = s[b * 256 + d];
}

extern "C" void kernel_launch(void* const* d_in, const int* in_sizes, int n_in,
                              void* d_out, int out_size, void* d_ws, size_t ws_size,
                              hipStream_t stream) {
  const float* x     = (const float*)d_in[0];
  const float* emb_W = (const float*)d_in[1];
  const float* emb_b = (const float*)d_in[2];
  const float* lat_W = (const float*)d_in[3];
  const float* lat_b = (const float*)d_in[4];
  const float* l2s_W = (const float*)d_in[5];
  const float* l2s_b = (const float*)d_in[6];
  const float* out_W = (const float*)d_in[7];
  const float* out_b = (const float*)d_in[8];

  float* ws = (float*)d_ws;
  float* h      = ws;                 // 8192*256   = 2097152
  float* xz     = h + 2097152;        // 8192*1024  = 8388608
  float* xc     = xz + 8388608;       // 8192*512   = 4194304
  float* dbl    = xc + 4194304;       // 8192*48    = 393216
  float* dtb    = dbl + 393216;       // 8192*512   = 4194304
  float* y      = dtb + 4194304;      // 8192*512   = 4194304
  float* pooled = y + 4194304;        // 4096
  float* s_sml  = pooled + 4096;      // 4096

  float* recon  = (float*)d_out;           // 8192*64
  float* latent = recon + 524288;          // 16*128

  dim3 blk(256);

  // h = x @ emb_W.T + emb_b
  hipLaunchKernelGGL((gemm_f32<0, true>), dim3(256 / 64, MROWS / 64), blk, 0, stream,
                     x, 64, emb_W, emb_b, h, MROWS, 256, 64);

  auto run_layer = [&](int base, int i) {
    const float* Win  = (const float*)d_in[base + 0] + (size_t)i * 1024 * 256;
    const float* cw   = (const float*)d_in[base + 1] + (size_t)i * 512 * 4;
    const float* cb   = (const float*)d_in[base + 2] + (size_t)i * 512;
    const float* Wx   = (const float*)d_in[base + 3] + (size_t)i * 48 * 512;
    const float* Wdt  = (const float*)d_in[base + 4] + (size_t)i * 512 * 16;
    const float* bdt  = (const float*)d_in[base + 5] + (size_t)i * 512;
    const float* Alog = (const float*)d_in[base + 6] + (size_t)i * 512 * 16;
    const float* Dpp  = (const float*)d_in[base + 7] + (size_t)i * 512;
    const float* Wout = (const float*)d_in[base + 8] + (size_t)i * 256 * 512;

    // xz = h @ Win.T
    hipLaunchKernelGGL((gemm_f32<0, false>), dim3(1024 / 64, MROWS / 64), blk, 0, stream,
                       h, 256, Win, nullptr, xz, MROWS, 1024, 256);
    // xc = silu(conv(xz[:, :512]) + cb)
    hipLaunchKernelGGL(conv_silu_kernel, dim3(MROWS * 512 / 256), blk, 0, stream,
                       xz, cw, cb, xc);
    // dbl = xc @ Wx.T  (N=48)
    hipLaunchKernelGGL((gemm_f32<0, false>), dim3(1, MROWS / 64), blk, 0, stream,
                       xc, 512, Wx, nullptr, dbl, MROWS, 48, 512);
    // dt = softplus(dbl[:, :16] @ Wdt.T + bdt)
    hipLaunchKernelGGL((gemm_f32<1, true>), dim3(512 / 64, MROWS / 64), blk, 0, stream,
                       dbl, 48, Wdt, bdt, dtb, MROWS, 512, 16);
    // y = (scan + xc*Dp) * silu(z)
    hipLaunchKernelGGL(scan_kernel, dim3(8192 / 16), blk, 0, stream,
                       xc, dtb, dbl, xz, Alog, Dpp, y);
    // h = y @ Wout.T
    hipLaunchKernelGGL((gemm_f32<0, false>), dim3(256 / 64, MROWS / 64), blk, 0, stream,
                       y, 512, Wout, nullptr, h, MROWS, 256, 512);
  };

  run_layer(9, 0);
  run_layer(9, 1);

  hipLaunchKernelGGL(pool_kernel, dim3(16), blk, 0, stream, h, pooled);
  hipLaunchKernelGGL(small_gemm_kernel, dim3((16 * 128 + 255) / 256), blk, 0, stream,
                     pooled, lat_W, lat_b, latent, 16, 128, 256);
  hipLaunchKernelGGL(small_gemm_kernel, dim3((16 * 256 + 255) / 256), blk, 0, stream,
                     latent, l2s_W, l2s_b, s_sml, 16, 256, 128);
  hipLaunchKernelGGL(bcast_kernel, dim3(8192 * 256 / 256), blk, 0, stream, s_sml, h);

  run_layer(18, 0);
  run_layer(18, 1);

  // recon = h @ out_W.T + out_b
  hipLaunchKernelGGL((gemm_f32<0, true>), dim3(1, MROWS / 64), blk, 0, stream,
                     h, 256, out_W, out_b, recon, MROWS, 64, 256);
}

// Round 2
// 1387.311 us; speedup vs baseline: 1.7703x; 1.7703x over previous
//
#include <hip/hip_runtime.h>
#include <hip/hip_bf16.h>

// LightweightMambaCodec: B=16 L=512 DIN=64 DM=256 DI=512 NL=2 LAT=128 N=16 K=4 R=16
// R1: chunked (3-phase) selective scan replaces latency-bound serial scan.

#define DEVINL __device__ __forceinline__

constexpr int MROWS = 16 * 512; // 8192

DEVINL float silu_f(float x) { return x / (1.f + __expf(-x)); }
DEVINL float softplus_f(float x) { return (x > 20.f) ? x : log1pf(__expf(x)); }

// C[M,N] = A[M,K] @ W[N,K]^T (+bias) (+act). A has row stride lda. W row-major NxK.
template<int ACT, bool BIAS>
__global__ __launch_bounds__(256) void gemm_f32(
    const float* __restrict__ A, int lda,
    const float* __restrict__ W,
    const float* __restrict__ bias,
    float* __restrict__ C,
    int M, int N, int K)
{
  constexpr int BM = 64, BN = 64, BK = 32;
  __shared__ float As[BK][BM + 4];
  __shared__ float Ws[BK][BN + 4];
  const int tid = threadIdx.x;
  const int bn0 = blockIdx.x * BN;
  const int bm0 = blockIdx.y * BM;
  const int tx = tid & 15;
  const int ty = tid >> 4;
  const int ar = tid >> 3;
  const int ac = (tid & 7) << 2;

  float acc[4][4] = {};
  for (int k0 = 0; k0 < K; k0 += BK) {
    #pragma unroll
    for (int rr = 0; rr < 2; rr++) {
      int r = ar + rr * 32;
      float4 v = make_float4(0.f, 0.f, 0.f, 0.f);
      if ((k0 + ac < K) && (bm0 + r < M))
        v = *(const float4*)(A + (size_t)(bm0 + r) * lda + k0 + ac);
      As[ac + 0][r] = v.x; As[ac + 1][r] = v.y; As[ac + 2][r] = v.z; As[ac + 3][r] = v.w;
      float4 w = make_float4(0.f, 0.f, 0.f, 0.f);
      if ((k0 + ac < K) && (bn0 + r < N))
        w = *(const float4*)(W + (size_t)(bn0 + r) * K + k0 + ac);
      Ws[ac + 0][r] = w.x; Ws[ac + 1][r] = w.y; Ws[ac + 2][r] = w.z; Ws[ac + 3][r] = w.w;
    }
    __syncthreads();
    #pragma unroll
    for (int kk = 0; kk < BK; kk++) {
      float4 a4 = *(const float4*)&As[kk][ty << 2];
      float4 b4 = *(const float4*)&Ws[kk][tx << 2];
      float av[4] = {a4.x, a4.y, a4.z, a4.w};
      float bv[4] = {b4.x, b4.y, b4.z, b4.w};
      #pragma unroll
      for (int i = 0; i < 4; i++)
        #pragma unroll
        for (int j = 0; j < 4; j++)
          acc[i][j] += av[i] * bv[j];
    }
    __syncthreads();
  }
  #pragma unroll
  for (int i = 0; i < 4; i++) {
    int r = bm0 + (ty << 2) + i;
    int c = bn0 + (tx << 2);
    if (r < M && c < N) {
      float4 o;
      float* po = &o.x;
      #pragma unroll
      for (int j = 0; j < 4; j++) {
        float v = acc[i][j];
        if (BIAS) v += bias[c + j];
        if (ACT == 1) v = softplus_f(v);
        po[j] = v;
      }
      *(float4*)(C + (size_t)r * N + c) = o;
    }
  }
}

// depthwise causal conv K=4, + bias + silu
__global__ __launch_bounds__(256) void conv_silu_kernel(
    const float* __restrict__ xz,
    const float* __restrict__ convw,
    const float* __restrict__ convb,
    float* __restrict__ xc)
{
  int idx = blockIdx.x * 256 + threadIdx.x;
  int d = idx & 511;
  int l = (idx >> 9) & 511;
  int b = idx >> 18;
  float acc = convb[d];
  #pragma unroll
  for (int k = 0; k < 4; k++) {
    int ll = l - 3 + k;
    if (ll >= 0) acc += convw[d * 4 + k] * xz[((size_t)(b * 512 + ll)) * 1024 + d];
  }
  xc[idx] = silu_f(acc);
}

// ---------- chunked selective scan ----------
// 16 chunks of T=32. S1: per-chunk (P, S) summaries. S2: inter-chunk scan.
// S3: replay with start states + fused epilogue.
// Block (S1/S3) = (b, dtile of 16 d, chunk c); 256 thr = 16 d x 16 n.

__global__ __launch_bounds__(256) void scan_part1(
    const float* __restrict__ xc,   // u (B,L,512)
    const float* __restrict__ dtb,  // (B,L,512)
    const float* __restrict__ dbl,  // (B,L,48)
    const float* __restrict__ Alog, // (512,16)
    float2* __restrict__ ps)        // (B,512,16,16) {P,S}
{
  __shared__ float dt_s[32][16], u_s[32][16], B_s[32][16];
  int bx = blockIdx.x;
  int c = bx & 15, dtile = (bx >> 4) & 31, b = bx >> 9;
  int d0 = dtile * 16;
  int t0 = c * 32;
  int tid = threadIdx.x;
  #pragma unroll
  for (int k = 0; k < 2; k++) {
    int e = tid + k * 256;
    int tl = e >> 4, i = e & 15;
    size_t row = (size_t)(b * 512 + t0 + tl);
    dt_s[tl][i] = dtb[row * 512 + d0 + i];
    u_s[tl][i]  = xc [row * 512 + d0 + i];
    B_s[tl][i]  = dbl[row * 48 + 16 + i];
  }
  __syncthreads();
  int n = tid & 15, dl = tid >> 4;
  float A_dn = -__expf(Alog[(d0 + dl) * 16 + n]);
  float P = 1.f, S = 0.f;
  #pragma unroll
  for (int j = 0; j < 32; j++) {
    float dtv = dt_s[j][dl];
    float a = __expf(dtv * A_dn);
    P *= a;
    S = a * S + dtv * u_s[j][dl] * B_s[j][n];
  }
  ps[((size_t)((b * 512 + d0 + dl) * 16 + n)) * 16 + c] = make_float2(P, S);
}

__global__ __launch_bounds__(256) void scan_part2(
    const float2* __restrict__ ps, float* __restrict__ hs)
{
  size_t tid = (size_t)blockIdx.x * 256 + threadIdx.x; // 131072 = (b,d,n)
  const float2* p = ps + tid * 16;
  float2 v[16];
  #pragma unroll
  for (int c = 0; c < 16; c++) v[c] = p[c];
  float h = 0.f;
  float o[16];
  #pragma unroll
  for (int c = 0; c < 16; c++) { o[c] = h; h = v[c].x * h + v[c].y; }
  float* q = hs + tid * 16;
  #pragma unroll
  for (int c = 0; c < 16; c++) q[c] = o[c];
}

__global__ __launch_bounds__(256) void scan_part3(
    const float* __restrict__ xc,
    const float* __restrict__ dtb,
    const float* __restrict__ dbl,
    const float* __restrict__ xz,   // z at col 512
    const float* __restrict__ Alog,
    const float* __restrict__ Dp,
    const float* __restrict__ hs,   // (B,512,16,16)
    float* __restrict__ y)          // (B,L,512)
{
  __shared__ float dt_s[32][16], u_s[32][16], B_s[32][16], C_s[32][16], z_s[32][16], y_s[32][16];
  int bx = blockIdx.x;
  int c = bx & 15, dtile = (bx >> 4) & 31, b = bx >> 9;
  int d0 = dtile * 16;
  int t0 = c * 32;
  int tid = threadIdx.x;
  #pragma unroll
  for (int k = 0; k < 2; k++) {
    int e = tid + k * 256;
    int tl = e >> 4, i = e & 15;
    size_t row = (size_t)(b * 512 + t0 + tl);
    dt_s[tl][i] = dtb[row * 512 + d0 + i];
    u_s[tl][i]  = xc [row * 512 + d0 + i];
    B_s[tl][i]  = dbl[row * 48 + 16 + i];
    C_s[tl][i]  = dbl[row * 48 + 32 + i];
    z_s[tl][i]  = xz [row * 1024 + 512 + d0 + i];
  }
  __syncthreads();
  int n = tid & 15, dl = tid >> 4;
  int d = d0 + dl;
  float A_dn = -__expf(Alog[d * 16 + n]);
  float Dv = Dp[d];
  float h = hs[((size_t)((b * 512 + d) * 16 + n)) * 16 + c];
  #pragma unroll
  for (int j = 0; j < 32; j++) {
    float dtv = dt_s[j][dl];
    float a = __expf(dtv * A_dn);
    h = a * h + dtv * u_s[j][dl] * B_s[j][n];
    float contrib = h * C_s[j][n];
    contrib += __shfl_xor(contrib, 1);
    contrib += __shfl_xor(contrib, 2);
    contrib += __shfl_xor(contrib, 4);
    contrib += __shfl_xor(contrib, 8);
    if (n == 0) y_s[j][dl] = contrib + u_s[j][dl] * Dv;
  }
  __syncthreads();
  #pragma unroll
  for (int k = 0; k < 2; k++) {
    int e = tid + k * 256;
    int tl = e >> 4, i = e & 15;
    size_t row = (size_t)(b * 512 + t0 + tl);
    y[row * 512 + d0 + i] = y_s[tl][i] * silu_f(z_s[tl][i]);
  }
}

__global__ void pool_kernel(const float* __restrict__ h, float* __restrict__ pooled) {
  int b = blockIdx.x, d = threadIdx.x;
  float s = 0.f;
  for (int l = 0; l < 512; l++) s += h[((size_t)(b * 512 + l)) * 256 + d];
  pooled[b * 256 + d] = s * (1.f / 512.f);
}

__global__ void small_gemm_kernel(const float* __restrict__ A, const float* __restrict__ W,
                                  const float* __restrict__ bias, float* __restrict__ C,
                                  int Mb, int N, int K) {
  int idx = blockIdx.x * blockDim.x + threadIdx.x;
  if (idx >= Mb * N) return;
  int b = idx / N, n = idx - b * N;
  float acc = bias[n];
  for (int k = 0; k < K; k++) acc += A[b * K + k] * W[n * K + k];
  C[idx] = acc;
}

__global__ void bcast_kernel(const float* __restrict__ s, float* __restrict__ h) {
  int idx = blockIdx.x * 256 + threadIdx.x;
  int d = idx & 255;
  int b = idx >> 17;
  h[idx] = s[b * 256 + d];
}

extern "C" void kernel_launch(void* const* d_in, const int* in_sizes, int n_in,
                              void* d_out, int out_size, void* d_ws, size_t ws_size,
                              hipStream_t stream) {
  const float* x     = (const float*)d_in[0];
  const float* emb_W = (const float*)d_in[1];
  const float* emb_b = (const float*)d_in[2];
  const float* lat_W = (const float*)d_in[3];
  const float* lat_b = (const float*)d_in[4];
  const float* l2s_W = (const float*)d_in[5];
  const float* l2s_b = (const float*)d_in[6];
  const float* out_W = (const float*)d_in[7];
  const float* out_b = (const float*)d_in[8];

  float* ws = (float*)d_ws;
  float* h      = ws;                 // 8192*256   = 2097152
  float* xz     = h + 2097152;        // 8192*1024  = 8388608
  float* xc     = xz + 8388608;       // 8192*512   = 4194304
  float* dbl    = xc + 4194304;       // 8192*48    = 393216
  float* dtb    = dbl + 393216;       // 8192*512   = 4194304
  float* y      = dtb + 4194304;      // 8192*512   = 4194304
  float* pooled = y + 4194304;        // 4096
  float* s_sml  = pooled + 4096;      // 4096
  float* psbuf  = s_sml + 4096;       // 131072*16*2 = 4194304 (float2 count 2097152)
  float* hsbuf  = psbuf + 4194304;    // 131072*16   = 2097152

  float* recon  = (float*)d_out;           // 8192*64
  float* latent = recon + 524288;          // 16*128

  dim3 blk(256);

  hipLaunchKernelGGL((gemm_f32<0, true>), dim3(256 / 64, MROWS / 64), blk, 0, stream,
                     x, 64, emb_W, emb_b, h, MROWS, 256, 64);

  auto run_layer = [&](int base, int i) {
    const float* Win  = (const float*)d_in[base + 0] + (size_t)i * 1024 * 256;
    const float* cw   = (const float*)d_in[base + 1] + (size_t)i * 512 * 4;
    const float* cb   = (const float*)d_in[base + 2] + (size_t)i * 512;
    const float* Wx   = (const float*)d_in[base + 3] + (size_t)i * 48 * 512;
    const float* Wdt  = (const float*)d_in[base + 4] + (size_t)i * 512 * 16;
    const float* bdt  = (const float*)d_in[base + 5] + (size_t)i * 512;
    const float* Alog = (const float*)d_in[base + 6] + (size_t)i * 512 * 16;
    const float* Dpp  = (const float*)d_in[base + 7] + (size_t)i * 512;
    const float* Wout = (const float*)d_in[base + 8] + (size_t)i * 256 * 512;

    hipLaunchKernelGGL((gemm_f32<0, false>), dim3(1024 / 64, MROWS / 64), blk, 0, stream,
                       h, 256, Win, nullptr, xz, MROWS, 1024, 256);
    hipLaunchKernelGGL(conv_silu_kernel, dim3(MROWS * 512 / 256), blk, 0, stream,
                       xz, cw, cb, xc);
    hipLaunchKernelGGL((gemm_f32<0, false>), dim3(1, MROWS / 64), blk, 0, stream,
                       xc, 512, Wx, nullptr, dbl, MROWS, 48, 512);
    hipLaunchKernelGGL((gemm_f32<1, true>), dim3(512 / 64, MROWS / 64), blk, 0, stream,
                       dbl, 48, Wdt, bdt, dtb, MROWS, 512, 16);
    // chunked scan
    hipLaunchKernelGGL(scan_part1, dim3(8192), blk, 0, stream,
                       xc, dtb, dbl, Alog, (float2*)psbuf);
    hipLaunchKernelGGL(scan_part2, dim3(131072 / 256), blk, 0, stream,
                       (const float2*)psbuf, hsbuf);
    hipLaunchKernelGGL(scan_part3, dim3(8192), blk, 0, stream,
                       xc, dtb, dbl, xz, Alog, Dpp, hsbuf, y);
    hipLaunchKernelGGL((gemm_f32<0, false>), dim3(256 / 64, MROWS / 64), blk, 0, stream,
                       y, 512, Wout, nullptr, h, MROWS, 256, 512);
  };

  run_layer(9, 0);
  run_layer(9, 1);

  hipLaunchKernelGGL(pool_kernel, dim3(16), blk, 0, stream, h, pooled);
  hipLaunchKernelGGL(small_gemm_kernel, dim3((16 * 128 + 255) / 256), blk, 0, stream,
                     pooled, lat_W, lat_b, latent, 16, 128, 256);
  hipLaunchKernelGGL(small_gemm_kernel, dim3((16 * 256 + 255) / 256), blk, 0, stream,
                     latent, l2s_W, l2s_b, s_sml, 16, 256, 128);
  hipLaunchKernelGGL(bcast_kernel, dim3(8192 * 256 / 256), blk, 0, stream, s_sml, h);

  run_layer(18, 0);
  run_layer(18, 1);

  hipLaunchKernelGGL((gemm_f32<0, true>), dim3(1, MROWS / 64), blk, 0, stream,
                     h, 256, out_W, out_b, recon, MROWS, 64, 256);
}

// Round 4
// 1009.649 us; speedup vs baseline: 2.4325x; 1.3741x over previous
//
#include <hip/hip_runtime.h>
#include <hip/hip_bf16.h>

// LightweightMambaCodec: B=16 L=512 DIN=64 DM=256 DI=512 NL=2 LAT=128 N=16 K=4 R=16
// R2 (resubmit after GPU acquisition timeout): split-bf16 (hi+lo) MFMA GEMMs replace
// fp32 VALU GEMMs; dt-proj fused into scan.

#define DEVINL __device__ __forceinline__

typedef unsigned short u16;
typedef short bf16x8 __attribute__((ext_vector_type(8)));
typedef float f32x4 __attribute__((ext_vector_type(4)));
typedef u16 ushort8 __attribute__((ext_vector_type(8)));
typedef u16 ushort4v __attribute__((ext_vector_type(4)));

constexpr int MROWS = 16 * 512; // 8192

DEVINL float silu_f(float x) { return x / (1.f + __expf(-x)); }
DEVINL float softplus_f(float x) { return (x > 20.f) ? x : log1pf(__expf(x)); }

DEVINL u16 f2bf(float x) {
  __hip_bfloat16 h = __float2bfloat16(x);
  return *reinterpret_cast<u16*>(&h);
}
DEVINL float bf2f(u16 u) {
  __hip_bfloat16 h;
  *reinterpret_cast<u16*>(&h) = u;
  return __bfloat162float(h);
}

// ---------------- split pre-pass ----------------
struct SplitList {
  const float* src[9];
  u16* hi[9];
  u16* lo[9];
  int n4[9];
};

__global__ __launch_bounds__(256) void split_kernel(SplitList sl, int total4) {
  int i = blockIdx.x * 256 + threadIdx.x;
  if (i >= total4) return;
  int t = 0, off = i;
  while (off >= sl.n4[t]) { off -= sl.n4[t]; ++t; }
  float4 v = *(const float4*)(sl.src[t] + (size_t)off * 4);
  float vv[4] = {v.x, v.y, v.z, v.w};
  ushort4v h, l;
  #pragma unroll
  for (int j = 0; j < 4; j++) {
    u16 hb = f2bf(vv[j]);
    h[j] = hb;
    l[j] = f2bf(vv[j] - bf2f(hb));
  }
  *(ushort4v*)(sl.hi[t] + (size_t)off * 4) = h;
  *(ushort4v*)(sl.lo[t] + (size_t)off * 4) = l;
}

// ---------------- split-bf16 MFMA GEMM ----------------
// C[M,N] = A[M,K] @ W[N,K]^T, A/W given as bf16 hi+lo pairs. acc in fp32.
// BM=128 BN=64 BK=32; 256 thr = 4 waves in 2x2; wave does 64x32 (4x2 16x16 frags).
template<bool BIAS, bool FOUT, bool SPLITOUT>
__global__ __launch_bounds__(256) void gemm_mfma(
    const u16* __restrict__ Ah, const u16* __restrict__ Al, int lda,
    const u16* __restrict__ Wh, const u16* __restrict__ Wl,
    const float* __restrict__ bias,
    float* __restrict__ C, u16* __restrict__ Chi, u16* __restrict__ Clo,
    int M, int N, int K)
{
  constexpr int BKP = 40; // +8 bf16 pad -> 2-way-max bank aliasing on b128 reads
  __shared__ u16 As[2][128][BKP];
  __shared__ u16 Ws[2][64][BKP];
  const int tid = threadIdx.x;
  const int bn0 = blockIdx.x * 64;
  const int bm0 = blockIdx.y * 128;
  const int w = tid >> 6, l = tid & 63;
  const int wm = w >> 1, wn = w & 1;
  const int lr = l & 15, lk = l >> 4;

  f32x4 acc[4][2] = {};

  for (int k0 = 0; k0 < K; k0 += 32) {
    #pragma unroll
    for (int q = 0; q < 2; q++) {
      int idx = tid + 256 * q;
      int r = idx >> 2, c8 = (idx & 3) * 8;
      size_t g = (size_t)(bm0 + r) * lda + k0 + c8;
      *(ushort8*)&As[0][r][c8] = *(const ushort8*)(Ah + g);
      *(ushort8*)&As[1][r][c8] = *(const ushort8*)(Al + g);
    }
    {
      int r = tid >> 2, c8 = (tid & 3) * 8;
      ushort8 vh = {0,0,0,0,0,0,0,0}, vl = {0,0,0,0,0,0,0,0};
      if (bn0 + r < N) {
        size_t g = (size_t)(bn0 + r) * K + k0 + c8;
        vh = *(const ushort8*)(Wh + g);
        vl = *(const ushort8*)(Wl + g);
      }
      *(ushort8*)&Ws[0][r][c8] = vh;
      *(ushort8*)&Ws[1][r][c8] = vl;
    }
    __syncthreads();

    bf16x8 afh[4], afl[4], wfh[2], wfl[2];
    #pragma unroll
    for (int i = 0; i < 4; i++) {
      int r = wm * 64 + i * 16 + lr;
      afh[i] = *(const bf16x8*)&As[0][r][lk * 8];
      afl[i] = *(const bf16x8*)&As[1][r][lk * 8];
    }
    #pragma unroll
    for (int j = 0; j < 2; j++) {
      int r = wn * 32 + j * 16 + lr;
      wfh[j] = *(const bf16x8*)&Ws[0][r][lk * 8];
      wfl[j] = *(const bf16x8*)&Ws[1][r][lk * 8];
    }
    #pragma unroll
    for (int i = 0; i < 4; i++)
      #pragma unroll
      for (int j = 0; j < 2; j++) {
        acc[i][j] = __builtin_amdgcn_mfma_f32_16x16x32_bf16(afh[i], wfh[j], acc[i][j], 0, 0, 0);
        acc[i][j] = __builtin_amdgcn_mfma_f32_16x16x32_bf16(afh[i], wfl[j], acc[i][j], 0, 0, 0);
        acc[i][j] = __builtin_amdgcn_mfma_f32_16x16x32_bf16(afl[i], wfh[j], acc[i][j], 0, 0, 0);
      }
    __syncthreads();
  }

  // epilogue: C/D layout col=lane&15, row=(lane>>4)*4+reg
  #pragma unroll
  for (int i = 0; i < 4; i++)
    #pragma unroll
    for (int j = 0; j < 2; j++) {
      int col = bn0 + wn * 32 + j * 16 + lr;
      if (col < N) {
        float bv = BIAS ? bias[col] : 0.f;
        #pragma unroll
        for (int rr = 0; rr < 4; rr++) {
          int row = bm0 + wm * 64 + i * 16 + lk * 4 + rr;
          float v = acc[i][j][rr] + bv;
          size_t o = (size_t)row * N + col;
          if constexpr (FOUT) C[o] = v;
          if constexpr (SPLITOUT) {
            u16 hb = f2bf(v);
            Chi[o] = hb;
            Clo[o] = f2bf(v - bf2f(hb));
          }
        }
      }
    }
}

// depthwise causal conv K=4, + bias + silu; outputs split bf16 xc
__global__ __launch_bounds__(256) void conv_silu_kernel(
    const float* __restrict__ xz,
    const float* __restrict__ convw,
    const float* __restrict__ convb,
    u16* __restrict__ xch, u16* __restrict__ xcl)
{
  int idx = blockIdx.x * 256 + threadIdx.x;
  int d = idx & 511;
  int l = (idx >> 9) & 511;
  int b = idx >> 18;
  float acc = convb[d];
  #pragma unroll
  for (int k = 0; k < 4; k++) {
    int ll = l - 3 + k;
    if (ll >= 0) acc += convw[d * 4 + k] * xz[((size_t)(b * 512 + ll)) * 1024 + d];
  }
  float v = silu_f(acc);
  u16 hb = f2bf(v);
  xch[idx] = hb;
  xcl[idx] = f2bf(v - bf2f(hb));
}

// ---------------- chunked scan (dt-proj fused) ----------------
__global__ __launch_bounds__(256) void scan_part1(
    const u16* __restrict__ xch, const u16* __restrict__ xcl,
    const float* __restrict__ dbl,
    const float* __restrict__ Wdt, const float* __restrict__ bdt,
    const float* __restrict__ Alog,
    float2* __restrict__ ps)
{
  __shared__ float dt_s[32][16], u_s[32][16], B_s[32][16], r_s[32][17], Wdt_s[16][17];
  int bx = blockIdx.x;
  int c = bx & 15, dtile = (bx >> 4) & 31, b = bx >> 9;
  int d0 = dtile * 16, t0 = c * 32;
  int tid = threadIdx.x;
  { int dd = tid >> 4, rr = tid & 15; Wdt_s[dd][rr] = Wdt[(d0 + dd) * 16 + rr]; }
  #pragma unroll
  for (int k = 0; k < 2; k++) {
    int e = tid + k * 256;
    int tl = e >> 4, i = e & 15;
    size_t row = (size_t)(b * 512 + t0 + tl);
    u_s[tl][i] = bf2f(xch[row * 512 + d0 + i]) + bf2f(xcl[row * 512 + d0 + i]);
    r_s[tl][i] = dbl[row * 48 + i];
    B_s[tl][i] = dbl[row * 48 + 16 + i];
  }
  __syncthreads();
  #pragma unroll
  for (int k = 0; k < 2; k++) {
    int e = tid + k * 256;
    int tl = e >> 4, i = e & 15;
    float a = bdt[d0 + i];
    #pragma unroll
    for (int r = 0; r < 16; r++) a += r_s[tl][r] * Wdt_s[i][r];
    dt_s[tl][i] = softplus_f(a);
  }
  __syncthreads();
  int n = tid & 15, dl = tid >> 4;
  float A_dn = -__expf(Alog[(d0 + dl) * 16 + n]);
  float P = 1.f, S = 0.f;
  #pragma unroll
  for (int j = 0; j < 32; j++) {
    float dtv = dt_s[j][dl];
    float a = __expf(dtv * A_dn);
    P *= a;
    S = a * S + dtv * u_s[j][dl] * B_s[j][n];
  }
  ps[((size_t)((b * 512 + d0 + dl) * 16 + n)) * 16 + c] = make_float2(P, S);
}

__global__ __launch_bounds__(256) void scan_part2(
    const float2* __restrict__ ps, float* __restrict__ hs)
{
  size_t tid = (size_t)blockIdx.x * 256 + threadIdx.x; // 131072 = (b,d,n)
  const float2* p = ps + tid * 16;
  float2 v[16];
  #pragma unroll
  for (int c = 0; c < 16; c++) v[c] = p[c];
  float h = 0.f;
  float o[16];
  #pragma unroll
  for (int c = 0; c < 16; c++) { o[c] = h; h = v[c].x * h + v[c].y; }
  float* q = hs + tid * 16;
  #pragma unroll
  for (int c = 0; c < 16; c++) q[c] = o[c];
}

__global__ __launch_bounds__(256) void scan_part3(
    const u16* __restrict__ xch, const u16* __restrict__ xcl,
    const float* __restrict__ dbl,
    const float* __restrict__ xz,   // z at col 512
    const float* __restrict__ Wdt, const float* __restrict__ bdt,
    const float* __restrict__ Alog, const float* __restrict__ Dp,
    const float* __restrict__ hs,
    u16* __restrict__ yh, u16* __restrict__ yl)
{
  __shared__ float dt_s[32][16], u_s[32][16], B_s[32][16], C_s[32][16], z_s[32][16], y_s[32][16];
  __shared__ float r_s[32][17], Wdt_s[16][17];
  int bx = blockIdx.x;
  int c = bx & 15, dtile = (bx >> 4) & 31, b = bx >> 9;
  int d0 = dtile * 16, t0 = c * 32;
  int tid = threadIdx.x;
  { int dd = tid >> 4, rr = tid & 15; Wdt_s[dd][rr] = Wdt[(d0 + dd) * 16 + rr]; }
  #pragma unroll
  for (int k = 0; k < 2; k++) {
    int e = tid + k * 256;
    int tl = e >> 4, i = e & 15;
    size_t row = (size_t)(b * 512 + t0 + tl);
    u_s[tl][i] = bf2f(xch[row * 512 + d0 + i]) + bf2f(xcl[row * 512 + d0 + i]);
    r_s[tl][i] = dbl[row * 48 + i];
    B_s[tl][i] = dbl[row * 48 + 16 + i];
    C_s[tl][i] = dbl[row * 48 + 32 + i];
    z_s[tl][i] = xz[row * 1024 + 512 + d0 + i];
  }
  __syncthreads();
  #pragma unroll
  for (int k = 0; k < 2; k++) {
    int e = tid + k * 256;
    int tl = e >> 4, i = e & 15;
    float a = bdt[d0 + i];
    #pragma unroll
    for (int r = 0; r < 16; r++) a += r_s[tl][r] * Wdt_s[i][r];
    dt_s[tl][i] = softplus_f(a);
  }
  __syncthreads();
  int n = tid & 15, dl = tid >> 4;
  int d = d0 + dl;
  float A_dn = -__expf(Alog[d * 16 + n]);
  float Dv = Dp[d];
  float h = hs[((size_t)((b * 512 + d) * 16 + n)) * 16 + c];
  #pragma unroll
  for (int j = 0; j < 32; j++) {
    float dtv = dt_s[j][dl];
    float a = __expf(dtv * A_dn);
    h = a * h + dtv * u_s[j][dl] * B_s[j][n];
    float contrib = h * C_s[j][n];
    contrib += __shfl_xor(contrib, 1);
    contrib += __shfl_xor(contrib, 2);
    contrib += __shfl_xor(contrib, 4);
    contrib += __shfl_xor(contrib, 8);
    if (n == 0) y_s[j][dl] = contrib + u_s[j][dl] * Dv;
  }
  __syncthreads();
  #pragma unroll
  for (int k = 0; k < 2; k++) {
    int e = tid + k * 256;
    int tl = e >> 4, i = e & 15;
    size_t row = (size_t)(b * 512 + t0 + tl);
    float v = y_s[tl][i] * silu_f(z_s[tl][i]);
    u16 hb = f2bf(v);
    yh[row * 512 + d0 + i] = hb;
    yl[row * 512 + d0 + i] = f2bf(v - bf2f(hb));
  }
}

__global__ void pool_kernel(const float* __restrict__ h, float* __restrict__ pooled) {
  int b = blockIdx.x, d = threadIdx.x;
  float s = 0.f;
  for (int l = 0; l < 512; l++) s += h[((size_t)(b * 512 + l)) * 256 + d];
  pooled[b * 256 + d] = s * (1.f / 512.f);
}

__global__ void small_gemm_kernel(const float* __restrict__ A, const float* __restrict__ W,
                                  const float* __restrict__ bias, float* __restrict__ C,
                                  int Mb, int N, int K) {
  int idx = blockIdx.x * blockDim.x + threadIdx.x;
  if (idx >= Mb * N) return;
  int b = idx / N, n = idx - b * N;
  float acc = bias[n];
  for (int k = 0; k < K; k++) acc += A[b * K + k] * W[n * K + k];
  C[idx] = acc;
}

__global__ void bcast_kernel(const float* __restrict__ s, u16* __restrict__ hh, u16* __restrict__ hl) {
  int idx = blockIdx.x * 256 + threadIdx.x; // over 8192*256
  int d = idx & 255;
  int b = idx >> 17;
  float v = s[b * 256 + d];
  u16 hb = f2bf(v);
  hh[idx] = hb;
  hl[idx] = f2bf(v - bf2f(hb));
}

extern "C" void kernel_launch(void* const* d_in, const int* in_sizes, int n_in,
                              void* d_out, int out_size, void* d_ws, size_t ws_size,
                              hipStream_t stream) {
  const float* x     = (const float*)d_in[0];
  const float* emb_W = (const float*)d_in[1];
  const float* emb_b = (const float*)d_in[2];
  const float* lat_W = (const float*)d_in[3];
  const float* lat_b = (const float*)d_in[4];
  const float* l2s_W = (const float*)d_in[5];
  const float* l2s_b = (const float*)d_in[6];
  const float* out_W = (const float*)d_in[7];
  const float* out_b = (const float*)d_in[8];

  char* base = (char*)d_ws;
  float*  h      = (float*) (base + 0);          //  8,388,608 B
  float*  xz     = (float*) (base + 8388608);    // 33,554,432
  float*  dbl    = (float*) (base + 41943040);   //  1,572,864
  float2* ps     = (float2*)(base + 43515904);   // 16,777,216
  float*  hs     = (float*) (base + 60293120);   //  8,388,608
  u16*    h_hi   = (u16*)   (base + 68681728);   //  4,194,304
  u16*    h_lo   = (u16*)   (base + 72876032);   //  4,194,304
  u16*    xc_hi  = (u16*)   (base + 77070336);   //  8,388,608
  u16*    xc_lo  = (u16*)   (base + 85458944);   //  8,388,608
  u16*    x_hi   = (u16*)   (base + 93847552);   //  1,048,576
  u16*    x_lo   = (u16*)   (base + 94896128);   //  1,048,576
  u16*    w_hi   = (u16*)   (base + 95944704);   //  3,407,872
  u16*    w_lo   = (u16*)   (base + 99352576);   //  3,407,872
  float*  pooled = (float*) (base + 102760448);  //     16,384
  float*  s_sml  = (float*) (base + 102776832);  //     16,384
  // y split aliases ps (dead once scan_part2 consumed it; Wout runs before next part1)
  u16* y_hi = (u16*)ps;
  u16* y_lo = (u16*)((char*)ps + 8388608);

  float* recon  = (float*)d_out;      // 8192*64
  float* latent = recon + 524288;     // 16*128

  dim3 blk(256);

  // ---- split pre-pass: x + all GEMM weights ----
  SplitList sl;
  const float* srcs[9] = {x, emb_W, out_W,
                          (const float*)d_in[9],  (const float*)d_in[12], (const float*)d_in[17],
                          (const float*)d_in[18], (const float*)d_in[21], (const float*)d_in[26]};
  size_t offs[9] = {0, 0, 16384, 32768, 557056, 606208, 868352, 1392640, 1441792};
  int    n4s[9]  = {131072, 4096, 4096, 131072, 12288, 65536, 131072, 12288, 65536};
  for (int t = 0; t < 9; t++) {
    sl.src[t] = srcs[t];
    sl.hi[t] = (t == 0) ? x_hi : w_hi + offs[t];
    sl.lo[t] = (t == 0) ? x_lo : w_lo + offs[t];
    sl.n4[t] = n4s[t];
  }
  int total4 = 131072 + 4096 + 4096 + 131072 + 12288 + 65536 + 131072 + 12288 + 65536; // 557056
  hipLaunchKernelGGL(split_kernel, dim3(total4 / 256), blk, 0, stream, sl, total4);

  // h = x @ emb_W.T + emb_b  (split out only)
  hipLaunchKernelGGL((gemm_mfma<true, false, true>), dim3(4, 64), blk, 0, stream,
                     x_hi, x_lo, 64, w_hi + 0, w_lo + 0, emb_b,
                     nullptr, h_hi, h_lo, MROWS, 256, 64);

  auto run_layer = [&](int base_in, size_t wpre, int i, bool foutH) {
    const float* cw   = (const float*)d_in[base_in + 1] + (size_t)i * 512 * 4;
    const float* cb   = (const float*)d_in[base_in + 2] + (size_t)i * 512;
    const float* Wdt  = (const float*)d_in[base_in + 4] + (size_t)i * 512 * 16;
    const float* bdt  = (const float*)d_in[base_in + 5] + (size_t)i * 512;
    const float* Alog = (const float*)d_in[base_in + 6] + (size_t)i * 512 * 16;
    const float* Dpp  = (const float*)d_in[base_in + 7] + (size_t)i * 512;
    const u16* WinH  = w_hi + wpre + (size_t)i * 262144;
    const u16* WinL  = w_lo + wpre + (size_t)i * 262144;
    const u16* WxH   = w_hi + wpre + 524288 + (size_t)i * 24576;
    const u16* WxL   = w_lo + wpre + 524288 + (size_t)i * 24576;
    const u16* WoutH = w_hi + wpre + 573440 + (size_t)i * 131072;
    const u16* WoutL = w_lo + wpre + 573440 + (size_t)i * 131072;

    // xz = h @ Win.T
    hipLaunchKernelGGL((gemm_mfma<false, true, false>), dim3(16, 64), blk, 0, stream,
                       h_hi, h_lo, 256, WinH, WinL, nullptr, xz, nullptr, nullptr, MROWS, 1024, 256);
    // xc = silu(conv(xz[:, :512]) + cb) -> split
    hipLaunchKernelGGL(conv_silu_kernel, dim3(MROWS * 512 / 256), blk, 0, stream,
                       xz, cw, cb, xc_hi, xc_lo);
    // dbl = xc @ Wx.T (N=48)
    hipLaunchKernelGGL((gemm_mfma<false, true, false>), dim3(1, 64), blk, 0, stream,
                       xc_hi, xc_lo, 512, WxH, WxL, nullptr, dbl, nullptr, nullptr, MROWS, 48, 512);
    // chunked scan (dt fused)
    hipLaunchKernelGGL(scan_part1, dim3(8192), blk, 0, stream,
                       xc_hi, xc_lo, dbl, Wdt, bdt, Alog, ps);
    hipLaunchKernelGGL(scan_part2, dim3(131072 / 256), blk, 0, stream,
                       (const float2*)ps, hs);
    hipLaunchKernelGGL(scan_part3, dim3(8192), blk, 0, stream,
                       xc_hi, xc_lo, dbl, xz, Wdt, bdt, Alog, Dpp, hs, y_hi, y_lo);
    // h = y @ Wout.T
    if (foutH)
      hipLaunchKernelGGL((gemm_mfma<false, true, true>), dim3(4, 64), blk, 0, stream,
                         y_hi, y_lo, 512, WoutH, WoutL, nullptr, h, h_hi, h_lo, MROWS, 256, 512);
    else
      hipLaunchKernelGGL((gemm_mfma<false, false, true>), dim3(4, 64), blk, 0, stream,
                         y_hi, y_lo, 512, WoutH, WoutL, nullptr, nullptr, h_hi, h_lo, MROWS, 256, 512);
  };

  run_layer(9, 32768, 0, false);
  run_layer(9, 32768, 1, true);   // pool needs f32 h

  hipLaunchKernelGGL(pool_kernel, dim3(16), blk, 0, stream, h, pooled);
  hipLaunchKernelGGL(small_gemm_kernel, dim3((16 * 128 + 255) / 256), blk, 0, stream,
                     pooled, lat_W, lat_b, latent, 16, 128, 256);
  hipLaunchKernelGGL(small_gemm_kernel, dim3((16 * 256 + 255) / 256), blk, 0, stream,
                     latent, l2s_W, l2s_b, s_sml, 16, 256, 128);
  hipLaunchKernelGGL(bcast_kernel, dim3(8192 * 256 / 256), blk, 0, stream, s_sml, h_hi, h_lo);

  run_layer(18, 868352, 0, false);
  run_layer(18, 868352, 1, false);

  // recon = h @ out_W.T + out_b
  hipLaunchKernelGGL((gemm_mfma<true, true, false>), dim3(1, 64), blk, 0, stream,
                     h_hi, h_lo, 256, w_hi + 16384, w_lo + 16384, out_b,
                     recon, nullptr, nullptr, MROWS, 64, 256);
}

// Round 5
// 877.941 us; speedup vs baseline: 2.7974x; 1.1500x over previous
//
#include <hip/hip_runtime.h>
#include <hip/hip_bf16.h>

// LightweightMambaCodec: B=16 L=512 DIN=64 DM=256 DI=512 NL=2 LAT=128 N=16 K=4 R=16
// R5: scan kernels rebuilt around DPP reduce (no LDS shuffles) + packed LDS operands
// + vectorized bf16 staging + coalesced ps/hs layout. GEMMs unchanged from R4.

#define DEVINL __device__ __forceinline__

typedef unsigned short u16;
typedef unsigned int u32;
typedef short bf16x8 __attribute__((ext_vector_type(8)));
typedef float f32x4 __attribute__((ext_vector_type(4)));
typedef u16 ushort8 __attribute__((ext_vector_type(8)));
typedef u16 ushort4v __attribute__((ext_vector_type(4)));

constexpr int MROWS = 16 * 512; // 8192

DEVINL float silu_f(float x) { return x / (1.f + __expf(-x)); }
DEVINL float softplus_f(float x) { return (x > 20.f) ? x : log1pf(__expf(x)); }

DEVINL u16 f2bf(float x) {
  __hip_bfloat16 h = __float2bfloat16(x);
  return *reinterpret_cast<u16*>(&h);
}
DEVINL float bf2f(u16 u) {
  __hip_bfloat16 h;
  *reinterpret_cast<u16*>(&h) = u;
  return __bfloat162float(h);
}

// circular 16-lane-row sum via DPP (VALU pipe, no LDS):
// xor1, xor2 give aligned-quad sums; row_ror:4/8 combine quads (quads stay aligned).
template<int CTRL> DEVINL float dpp_add_step(float v) {
  int s = __builtin_amdgcn_update_dpp(0, __float_as_int(v), CTRL, 0xF, 0xF, true);
  return v + __int_as_float(s);
}
DEVINL float dpp_sum16(float v) {
  v = dpp_add_step<0xB1>(v);   // quad_perm(1,0,3,2)  xor1
  v = dpp_add_step<0x4E>(v);   // quad_perm(2,3,0,1)  xor2
  v = dpp_add_step<0x124>(v);  // row_ror:4
  v = dpp_add_step<0x128>(v);  // row_ror:8
  return v;
}

// ---------------- split pre-pass ----------------
struct SplitList {
  const float* src[9];
  u16* hi[9];
  u16* lo[9];
  int n4[9];
};

__global__ __launch_bounds__(256) void split_kernel(SplitList sl, int total4) {
  int i = blockIdx.x * 256 + threadIdx.x;
  if (i >= total4) return;
  int t = 0, off = i;
  while (off >= sl.n4[t]) { off -= sl.n4[t]; ++t; }
  float4 v = *(const float4*)(sl.src[t] + (size_t)off * 4);
  float vv[4] = {v.x, v.y, v.z, v.w};
  ushort4v h, l;
  #pragma unroll
  for (int j = 0; j < 4; j++) {
    u16 hb = f2bf(vv[j]);
    h[j] = hb;
    l[j] = f2bf(vv[j] - bf2f(hb));
  }
  *(ushort4v*)(sl.hi[t] + (size_t)off * 4) = h;
  *(ushort4v*)(sl.lo[t] + (size_t)off * 4) = l;
}

// ---------------- split-bf16 MFMA GEMM (unchanged from R4) ----------------
template<bool BIAS, bool FOUT, bool SPLITOUT>
__global__ __launch_bounds__(256) void gemm_mfma(
    const u16* __restrict__ Ah, const u16* __restrict__ Al, int lda,
    const u16* __restrict__ Wh, const u16* __restrict__ Wl,
    const float* __restrict__ bias,
    float* __restrict__ C, u16* __restrict__ Chi, u16* __restrict__ Clo,
    int M, int N, int K)
{
  constexpr int BKP = 40;
  __shared__ u16 As[2][128][BKP];
  __shared__ u16 Ws[2][64][BKP];
  const int tid = threadIdx.x;
  const int bn0 = blockIdx.x * 64;
  const int bm0 = blockIdx.y * 128;
  const int w = tid >> 6, l = tid & 63;
  const int wm = w >> 1, wn = w & 1;
  const int lr = l & 15, lk = l >> 4;

  f32x4 acc[4][2] = {};

  for (int k0 = 0; k0 < K; k0 += 32) {
    #pragma unroll
    for (int q = 0; q < 2; q++) {
      int idx = tid + 256 * q;
      int r = idx >> 2, c8 = (idx & 3) * 8;
      size_t g = (size_t)(bm0 + r) * lda + k0 + c8;
      *(ushort8*)&As[0][r][c8] = *(const ushort8*)(Ah + g);
      *(ushort8*)&As[1][r][c8] = *(const ushort8*)(Al + g);
    }
    {
      int r = tid >> 2, c8 = (tid & 3) * 8;
      ushort8 vh = {0,0,0,0,0,0,0,0}, vl = {0,0,0,0,0,0,0,0};
      if (bn0 + r < N) {
        size_t g = (size_t)(bn0 + r) * K + k0 + c8;
        vh = *(const ushort8*)(Wh + g);
        vl = *(const ushort8*)(Wl + g);
      }
      *(ushort8*)&Ws[0][r][c8] = vh;
      *(ushort8*)&Ws[1][r][c8] = vl;
    }
    __syncthreads();

    bf16x8 afh[4], afl[4], wfh[2], wfl[2];
    #pragma unroll
    for (int i = 0; i < 4; i++) {
      int r = wm * 64 + i * 16 + lr;
      afh[i] = *(const bf16x8*)&As[0][r][lk * 8];
      afl[i] = *(const bf16x8*)&As[1][r][lk * 8];
    }
    #pragma unroll
    for (int j = 0; j < 2; j++) {
      int r = wn * 32 + j * 16 + lr;
      wfh[j] = *(const bf16x8*)&Ws[0][r][lk * 8];
      wfl[j] = *(const bf16x8*)&Ws[1][r][lk * 8];
    }
    #pragma unroll
    for (int i = 0; i < 4; i++)
      #pragma unroll
      for (int j = 0; j < 2; j++) {
        acc[i][j] = __builtin_amdgcn_mfma_f32_16x16x32_bf16(afh[i], wfh[j], acc[i][j], 0, 0, 0);
        acc[i][j] = __builtin_amdgcn_mfma_f32_16x16x32_bf16(afh[i], wfl[j], acc[i][j], 0, 0, 0);
        acc[i][j] = __builtin_amdgcn_mfma_f32_16x16x32_bf16(afl[i], wfh[j], acc[i][j], 0, 0, 0);
      }
    __syncthreads();
  }

  #pragma unroll
  for (int i = 0; i < 4; i++)
    #pragma unroll
    for (int j = 0; j < 2; j++) {
      int col = bn0 + wn * 32 + j * 16 + lr;
      if (col < N) {
        float bv = BIAS ? bias[col] : 0.f;
        #pragma unroll
        for (int rr = 0; rr < 4; rr++) {
          int row = bm0 + wm * 64 + i * 16 + lk * 4 + rr;
          float v = acc[i][j][rr] + bv;
          size_t o = (size_t)row * N + col;
          if constexpr (FOUT) C[o] = v;
          if constexpr (SPLITOUT) {
            u16 hb = f2bf(v);
            Chi[o] = hb;
            Clo[o] = f2bf(v - bf2f(hb));
          }
        }
      }
    }
}

// depthwise causal conv K=4, + bias + silu; outputs split bf16 xc
__global__ __launch_bounds__(256) void conv_silu_kernel(
    const float* __restrict__ xz,
    const float* __restrict__ convw,
    const float* __restrict__ convb,
    u16* __restrict__ xch, u16* __restrict__ xcl)
{
  int idx = blockIdx.x * 256 + threadIdx.x;
  int d = idx & 511;
  int l = (idx >> 9) & 511;
  int b = idx >> 18;
  float acc = convb[d];
  #pragma unroll
  for (int k = 0; k < 4; k++) {
    int ll = l - 3 + k;
    if (ll >= 0) acc += convw[d * 4 + k] * xz[((size_t)(b * 512 + ll)) * 1024 + d];
  }
  float v = silu_f(acc);
  u16 hb = f2bf(v);
  xch[idx] = hb;
  xcl[idx] = f2bf(v - bf2f(hb));
}

// ---------------- chunked scan ----------------
// ps/hs layout: [chunk c][ (b*512+d)*16 + n ]  (contiguous per c -> coalesced everywhere)

__global__ __launch_bounds__(256) void scan_part1(
    const u16* __restrict__ xch, const u16* __restrict__ xcl,
    const float* __restrict__ dbl,
    const float* __restrict__ Wdt, const float* __restrict__ bdt,
    const float* __restrict__ Alog,
    float2* __restrict__ ps)
{
  __shared__ float2 dw_s[32][16];      // (dt, dt*u)
  __shared__ float B_s[32][16];
  __shared__ float u_s[32][16];
  __shared__ float r_s[32][17];
  __shared__ float Wdt_s[16][17];
  int bx = blockIdx.x;
  int c = bx & 15, dtile = (bx >> 4) & 31, b = bx >> 9;
  int d0 = dtile * 16, t0 = c * 32;
  int tid = threadIdx.x;
  { int dd = tid >> 4, rr = tid & 15; Wdt_s[dd][rr] = Wdt[(d0 + dd) * 16 + rr]; }
  const int tl = tid >> 3, i2 = (tid & 7) * 2;
  const size_t row = (size_t)(b * 512 + t0 + tl);
  {
    u32 uh = *(const u32*)(xch + row * 512 + d0 + i2);
    u32 ul = *(const u32*)(xcl + row * 512 + d0 + i2);
    u_s[tl][i2]     = bf2f((u16)(uh & 0xFFFF)) + bf2f((u16)(ul & 0xFFFF));
    u_s[tl][i2 + 1] = bf2f((u16)(uh >> 16))    + bf2f((u16)(ul >> 16));
    float2 rv = *(const float2*)(dbl + row * 48 + i2);
    r_s[tl][i2] = rv.x; r_s[tl][i2 + 1] = rv.y;
    float2 bv = *(const float2*)(dbl + row * 48 + 16 + i2);
    B_s[tl][i2] = bv.x; B_s[tl][i2 + 1] = bv.y;
  }
  __syncthreads();
  {
    float a0 = bdt[d0 + i2], a1 = bdt[d0 + i2 + 1];
    #pragma unroll
    for (int r = 0; r < 16; r++) {
      float rv = r_s[tl][r];
      a0 += rv * Wdt_s[i2][r];
      a1 += rv * Wdt_s[i2 + 1][r];
    }
    float dt0 = softplus_f(a0), dt1 = softplus_f(a1);
    dw_s[tl][i2]     = make_float2(dt0, dt0 * u_s[tl][i2]);
    dw_s[tl][i2 + 1] = make_float2(dt1, dt1 * u_s[tl][i2 + 1]);
  }
  __syncthreads();
  int n = tid & 15, dl = tid >> 4;
  float A_dn = -__expf(Alog[(d0 + dl) * 16 + n]);
  float P = 1.f, S = 0.f;
  #pragma unroll
  for (int j = 0; j < 32; j++) {
    float2 dw = dw_s[j][dl];
    float a = __expf(dw.x * A_dn);
    P *= a;
    S = a * S + dw.y * B_s[j][n];
  }
  ps[(size_t)c * 131072 + (size_t)(b * 512 + d0 + dl) * 16 + n] = make_float2(P, S);
}

__global__ __launch_bounds__(256) void scan_part2(
    const float2* __restrict__ ps, float* __restrict__ hs)
{
  int idx = blockIdx.x * 256 + threadIdx.x; // 131072 = (b,d,n)
  float h = 0.f;
  #pragma unroll
  for (int c = 0; c < 16; c++) {
    float2 v = ps[(size_t)c * 131072 + idx];
    hs[(size_t)c * 131072 + idx] = h;
    h = v.x * h + v.y;
  }
}

__global__ __launch_bounds__(256) void scan_part3(
    const u16* __restrict__ xch, const u16* __restrict__ xcl,
    const float* __restrict__ dbl,
    const float* __restrict__ xz,   // z at col 512
    const float* __restrict__ Wdt, const float* __restrict__ bdt,
    const float* __restrict__ Alog, const float* __restrict__ Dp,
    const float* __restrict__ hs,
    u16* __restrict__ yh, u16* __restrict__ yl)
{
  __shared__ float4 dwu_s[32][16];     // (dt, dt*u, u, -)
  __shared__ float2 bc_s[32][16];      // (B, C)
  __shared__ float z_s[32][16];
  __shared__ float uy_s[32][16];       // u during staging/dt-pass; y during main/epilogue
  __shared__ float r_s[32][17];
  __shared__ float Wdt_s[16][17];
  int bx = blockIdx.x;
  int c = bx & 15, dtile = (bx >> 4) & 31, b = bx >> 9;
  int d0 = dtile * 16, t0 = c * 32;
  int tid = threadIdx.x;
  { int dd = tid >> 4, rr = tid & 15; Wdt_s[dd][rr] = Wdt[(d0 + dd) * 16 + rr]; }
  const int tl = tid >> 3, i2 = (tid & 7) * 2;
  const size_t row = (size_t)(b * 512 + t0 + tl);
  {
    u32 uh = *(const u32*)(xch + row * 512 + d0 + i2);
    u32 ul = *(const u32*)(xcl + row * 512 + d0 + i2);
    uy_s[tl][i2]     = bf2f((u16)(uh & 0xFFFF)) + bf2f((u16)(ul & 0xFFFF));
    uy_s[tl][i2 + 1] = bf2f((u16)(uh >> 16))    + bf2f((u16)(ul >> 16));
    float2 rv = *(const float2*)(dbl + row * 48 + i2);
    r_s[tl][i2] = rv.x; r_s[tl][i2 + 1] = rv.y;
    float2 bv = *(const float2*)(dbl + row * 48 + 16 + i2);
    float2 cv = *(const float2*)(dbl + row * 48 + 32 + i2);
    bc_s[tl][i2]     = make_float2(bv.x, cv.x);
    bc_s[tl][i2 + 1] = make_float2(bv.y, cv.y);
    float2 zv = *(const float2*)(xz + row * 1024 + 512 + d0 + i2);
    z_s[tl][i2] = zv.x; z_s[tl][i2 + 1] = zv.y;
  }
  __syncthreads();
  {
    float a0 = bdt[d0 + i2], a1 = bdt[d0 + i2 + 1];
    #pragma unroll
    for (int r = 0; r < 16; r++) {
      float rv = r_s[tl][r];
      a0 += rv * Wdt_s[i2][r];
      a1 += rv * Wdt_s[i2 + 1][r];
    }
    float dt0 = softplus_f(a0), dt1 = softplus_f(a1);
    float u0 = uy_s[tl][i2], u1 = uy_s[tl][i2 + 1];
    dwu_s[tl][i2]     = make_float4(dt0, dt0 * u0, u0, 0.f);
    dwu_s[tl][i2 + 1] = make_float4(dt1, dt1 * u1, u1, 0.f);
  }
  __syncthreads();
  int n = tid & 15, dl = tid >> 4;
  int d = d0 + dl;
  float A_dn = -__expf(Alog[d * 16 + n]);
  float Dv = Dp[d];
  float h = hs[(size_t)c * 131072 + (size_t)(b * 512 + d) * 16 + n];
  #pragma unroll
  for (int j = 0; j < 32; j++) {
    float4 dwu = dwu_s[j][dl];
    float2 bc = bc_s[j][n];
    float a = __expf(dwu.x * A_dn);
    h = a * h + dwu.y * bc.x;
    float contrib = dpp_sum16(h * bc.y);
    if (n == 0) uy_s[j][dl] = contrib + dwu.z * Dv;   // y value
  }
  __syncthreads();
  {
    float v0 = uy_s[tl][i2]     * silu_f(z_s[tl][i2]);
    float v1 = uy_s[tl][i2 + 1] * silu_f(z_s[tl][i2 + 1]);
    u16 h0 = f2bf(v0), h1 = f2bf(v1);
    u32 hp = (u32)h0 | ((u32)h1 << 16);
    u32 lp = (u32)f2bf(v0 - bf2f(h0)) | ((u32)f2bf(v1 - bf2f(h1)) << 16);
    *(u32*)(yh + row * 512 + d0 + i2) = hp;
    *(u32*)(yl + row * 512 + d0 + i2) = lp;
  }
}

__global__ void pool_kernel(const float* __restrict__ h, float* __restrict__ pooled) {
  int b = blockIdx.x, d = threadIdx.x;
  float s = 0.f;
  for (int l = 0; l < 512; l++) s += h[((size_t)(b * 512 + l)) * 256 + d];
  pooled[b * 256 + d] = s * (1.f / 512.f);
}

__global__ void small_gemm_kernel(const float* __restrict__ A, const float* __restrict__ W,
                                  const float* __restrict__ bias, float* __restrict__ C,
                                  int Mb, int N, int K) {
  int idx = blockIdx.x * blockDim.x + threadIdx.x;
  if (idx >= Mb * N) return;
  int b = idx / N, n = idx - b * N;
  float acc = bias[n];
  for (int k = 0; k < K; k++) acc += A[b * K + k] * W[n * K + k];
  C[idx] = acc;
}

__global__ void bcast_kernel(const float* __restrict__ s, u16* __restrict__ hh, u16* __restrict__ hl) {
  int idx = blockIdx.x * 256 + threadIdx.x; // over 8192*256
  int d = idx & 255;
  int b = idx >> 17;
  float v = s[b * 256 + d];
  u16 hb = f2bf(v);
  hh[idx] = hb;
  hl[idx] = f2bf(v - bf2f(hb));
}

extern "C" void kernel_launch(void* const* d_in, const int* in_sizes, int n_in,
                              void* d_out, int out_size, void* d_ws, size_t ws_size,
                              hipStream_t stream) {
  const float* x     = (const float*)d_in[0];
  const float* emb_W = (const float*)d_in[1];
  const float* emb_b = (const float*)d_in[2];
  const float* lat_W = (const float*)d_in[3];
  const float* lat_b = (const float*)d_in[4];
  const float* l2s_W = (const float*)d_in[5];
  const float* l2s_b = (const float*)d_in[6];
  const float* out_W = (const float*)d_in[7];
  const float* out_b = (const float*)d_in[8];

  char* base = (char*)d_ws;
  float*  h      = (float*) (base + 0);          //  8,388,608 B
  float*  xz     = (float*) (base + 8388608);    // 33,554,432
  float*  dbl    = (float*) (base + 41943040);   //  1,572,864
  float2* ps     = (float2*)(base + 43515904);   // 16,777,216
  float*  hs     = (float*) (base + 60293120);   //  8,388,608
  u16*    h_hi   = (u16*)   (base + 68681728);   //  4,194,304
  u16*    h_lo   = (u16*)   (base + 72876032);   //  4,194,304
  u16*    xc_hi  = (u16*)   (base + 77070336);   //  8,388,608
  u16*    xc_lo  = (u16*)   (base + 85458944);   //  8,388,608
  u16*    x_hi   = (u16*)   (base + 93847552);   //  1,048,576
  u16*    x_lo   = (u16*)   (base + 94896128);   //  1,048,576
  u16*    w_hi   = (u16*)   (base + 95944704);   //  3,407,872
  u16*    w_lo   = (u16*)   (base + 99352576);   //  3,407,872
  float*  pooled = (float*) (base + 102760448);  //     16,384
  float*  s_sml  = (float*) (base + 102776832);  //     16,384
  // y split aliases ps (ps dead once scan_part2 consumed it; Wout runs before next part1)
  u16* y_hi = (u16*)ps;
  u16* y_lo = (u16*)((char*)ps + 8388608);

  float* recon  = (float*)d_out;      // 8192*64
  float* latent = recon + 524288;     // 16*128

  dim3 blk(256);

  // ---- split pre-pass: x + all GEMM weights ----
  SplitList sl;
  const float* srcs[9] = {x, emb_W, out_W,
                          (const float*)d_in[9],  (const float*)d_in[12], (const float*)d_in[17],
                          (const float*)d_in[18], (const float*)d_in[21], (const float*)d_in[26]};
  size_t offs[9] = {0, 0, 16384, 32768, 557056, 606208, 868352, 1392640, 1441792};
  int    n4s[9]  = {131072, 4096, 4096, 131072, 12288, 65536, 131072, 12288, 65536};
  for (int t = 0; t < 9; t++) {
    sl.src[t] = srcs[t];
    sl.hi[t] = (t == 0) ? x_hi : w_hi + offs[t];
    sl.lo[t] = (t == 0) ? x_lo : w_lo + offs[t];
    sl.n4[t] = n4s[t];
  }
  int total4 = 557056;
  hipLaunchKernelGGL(split_kernel, dim3(total4 / 256), blk, 0, stream, sl, total4);

  // h = x @ emb_W.T + emb_b  (split out only)
  hipLaunchKernelGGL((gemm_mfma<true, false, true>), dim3(4, 64), blk, 0, stream,
                     x_hi, x_lo, 64, w_hi + 0, w_lo + 0, emb_b,
                     nullptr, h_hi, h_lo, MROWS, 256, 64);

  auto run_layer = [&](int base_in, size_t wpre, int i, bool foutH) {
    const float* cw   = (const float*)d_in[base_in + 1] + (size_t)i * 512 * 4;
    const float* cb   = (const float*)d_in[base_in + 2] + (size_t)i * 512;
    const float* Wdt  = (const float*)d_in[base_in + 4] + (size_t)i * 512 * 16;
    const float* bdt  = (const float*)d_in[base_in + 5] + (size_t)i * 512;
    const float* Alog = (const float*)d_in[base_in + 6] + (size_t)i * 512 * 16;
    const float* Dpp  = (const float*)d_in[base_in + 7] + (size_t)i * 512;
    const u16* WinH  = w_hi + wpre + (size_t)i * 262144;
    const u16* WinL  = w_lo + wpre + (size_t)i * 262144;
    const u16* WxH   = w_hi + wpre + 524288 + (size_t)i * 24576;
    const u16* WxL   = w_lo + wpre + 524288 + (size_t)i * 24576;
    const u16* WoutH = w_hi + wpre + 573440 + (size_t)i * 131072;
    const u16* WoutL = w_lo + wpre + 573440 + (size_t)i * 131072;

    // xz = h @ Win.T
    hipLaunchKernelGGL((gemm_mfma<false, true, false>), dim3(16, 64), blk, 0, stream,
                       h_hi, h_lo, 256, WinH, WinL, nullptr, xz, nullptr, nullptr, MROWS, 1024, 256);
    // xc = silu(conv(xz[:, :512]) + cb) -> split
    hipLaunchKernelGGL(conv_silu_kernel, dim3(MROWS * 512 / 256), blk, 0, stream,
                       xz, cw, cb, xc_hi, xc_lo);
    // dbl = xc @ Wx.T (N=48)
    hipLaunchKernelGGL((gemm_mfma<false, true, false>), dim3(1, 64), blk, 0, stream,
                       xc_hi, xc_lo, 512, WxH, WxL, nullptr, dbl, nullptr, nullptr, MROWS, 48, 512);
    // chunked scan (dt fused)
    hipLaunchKernelGGL(scan_part1, dim3(8192), blk, 0, stream,
                       xc_hi, xc_lo, dbl, Wdt, bdt, Alog, ps);
    hipLaunchKernelGGL(scan_part2, dim3(131072 / 256), blk, 0, stream,
                       (const float2*)ps, hs);
    hipLaunchKernelGGL(scan_part3, dim3(8192), blk, 0, stream,
                       xc_hi, xc_lo, dbl, xz, Wdt, bdt, Alog, Dpp, hs, y_hi, y_lo);
    // h = y @ Wout.T
    if (foutH)
      hipLaunchKernelGGL((gemm_mfma<false, true, true>), dim3(4, 64), blk, 0, stream,
                         y_hi, y_lo, 512, WoutH, WoutL, nullptr, h, h_hi, h_lo, MROWS, 256, 512);
    else
      hipLaunchKernelGGL((gemm_mfma<false, false, true>), dim3(4, 64), blk, 0, stream,
                         y_hi, y_lo, 512, WoutH, WoutL, nullptr, nullptr, h_hi, h_lo, MROWS, 256, 512);
  };

  run_layer(9, 32768, 0, false);
  run_layer(9, 32768, 1, true);   // pool needs f32 h

  hipLaunchKernelGGL(pool_kernel, dim3(16), blk, 0, stream, h, pooled);
  hipLaunchKernelGGL(small_gemm_kernel, dim3((16 * 128 + 255) / 256), blk, 0, stream,
                     pooled, lat_W, lat_b, latent, 16, 128, 256);
  hipLaunchKernelGGL(small_gemm_kernel, dim3((16 * 256 + 255) / 256), blk, 0, stream,
                     latent, l2s_W, l2s_b, s_sml, 16, 256, 128);
  hipLaunchKernelGGL(bcast_kernel, dim3(8192 * 256 / 256), blk, 0, stream, s_sml, h_hi, h_lo);

  run_layer(18, 868352, 0, false);
  run_layer(18, 868352, 1, false);

  // recon = h @ out_W.T + out_b
  hipLaunchKernelGGL((gemm_mfma<true, true, false>), dim3(1, 64), blk, 0, stream,
                     h_hi, h_lo, 256, w_hi + 16384, w_lo + 16384, out_b,
                     recon, nullptr, nullptr, MROWS, 64, 256);
}

// Round 8
// 845.433 us; speedup vs baseline: 2.9050x; 1.0385x over previous
//
#include <hip/hip_runtime.h>
#include <hip/hip_bf16.h>

// LightweightMambaCodec: B=16 L=512 DIN=64 DM=256 DI=512 NL=2 LAT=128 N=16 K=4 R=16
// R6 (2nd resubmit after GPU acquisition timeouts): scan restructured — one thread
// per (b,d) holds all 16 n-states in registers. No cross-lane reduce, no LDS; dbl
// operands via wave-uniform (scalar) loads. GEMMs unchanged from R4/R5.

#define DEVINL __device__ __forceinline__

typedef unsigned short u16;
typedef unsigned int u32;
typedef short bf16x8 __attribute__((ext_vector_type(8)));
typedef float f32x4 __attribute__((ext_vector_type(4)));
typedef u16 ushort8 __attribute__((ext_vector_type(8)));
typedef u16 ushort4v __attribute__((ext_vector_type(4)));

constexpr int MROWS = 16 * 512; // 8192

DEVINL float silu_f(float x) { return x / (1.f + __expf(-x)); }
DEVINL float softplus_f(float x) { return (x > 20.f) ? x : log1pf(__expf(x)); }

DEVINL u16 f2bf(float x) {
  __hip_bfloat16 h = __float2bfloat16(x);
  return *reinterpret_cast<u16*>(&h);
}
DEVINL float bf2f(u16 u) {
  __hip_bfloat16 h;
  *reinterpret_cast<u16*>(&h) = u;
  return __bfloat162float(h);
}

// ---------------- split pre-pass ----------------
struct SplitList {
  const float* src[9];
  u16* hi[9];
  u16* lo[9];
  int n4[9];
};

__global__ __launch_bounds__(256) void split_kernel(SplitList sl, int total4) {
  int i = blockIdx.x * 256 + threadIdx.x;
  if (i >= total4) return;
  int t = 0, off = i;
  while (off >= sl.n4[t]) { off -= sl.n4[t]; ++t; }
  float4 v = *(const float4*)(sl.src[t] + (size_t)off * 4);
  float vv[4] = {v.x, v.y, v.z, v.w};
  ushort4v h, l;
  #pragma unroll
  for (int j = 0; j < 4; j++) {
    u16 hb = f2bf(vv[j]);
    h[j] = hb;
    l[j] = f2bf(vv[j] - bf2f(hb));
  }
  *(ushort4v*)(sl.hi[t] + (size_t)off * 4) = h;
  *(ushort4v*)(sl.lo[t] + (size_t)off * 4) = l;
}

// ---------------- split-bf16 MFMA GEMM (unchanged) ----------------
template<bool BIAS, bool FOUT, bool SPLITOUT>
__global__ __launch_bounds__(256) void gemm_mfma(
    const u16* __restrict__ Ah, const u16* __restrict__ Al, int lda,
    const u16* __restrict__ Wh, const u16* __restrict__ Wl,
    const float* __restrict__ bias,
    float* __restrict__ C, u16* __restrict__ Chi, u16* __restrict__ Clo,
    int M, int N, int K)
{
  constexpr int BKP = 40;
  __shared__ u16 As[2][128][BKP];
  __shared__ u16 Ws[2][64][BKP];
  const int tid = threadIdx.x;
  const int bn0 = blockIdx.x * 64;
  const int bm0 = blockIdx.y * 128;
  const int w = tid >> 6, l = tid & 63;
  const int wm = w >> 1, wn = w & 1;
  const int lr = l & 15, lk = l >> 4;

  f32x4 acc[4][2] = {};

  for (int k0 = 0; k0 < K; k0 += 32) {
    #pragma unroll
    for (int q = 0; q < 2; q++) {
      int idx = tid + 256 * q;
      int r = idx >> 2, c8 = (idx & 3) * 8;
      size_t g = (size_t)(bm0 + r) * lda + k0 + c8;
      *(ushort8*)&As[0][r][c8] = *(const ushort8*)(Ah + g);
      *(ushort8*)&As[1][r][c8] = *(const ushort8*)(Al + g);
    }
    {
      int r = tid >> 2, c8 = (tid & 3) * 8;
      ushort8 vh = {0,0,0,0,0,0,0,0}, vl = {0,0,0,0,0,0,0,0};
      if (bn0 + r < N) {
        size_t g = (size_t)(bn0 + r) * K + k0 + c8;
        vh = *(const ushort8*)(Wh + g);
        vl = *(const ushort8*)(Wl + g);
      }
      *(ushort8*)&Ws[0][r][c8] = vh;
      *(ushort8*)&Ws[1][r][c8] = vl;
    }
    __syncthreads();

    bf16x8 afh[4], afl[4], wfh[2], wfl[2];
    #pragma unroll
    for (int i = 0; i < 4; i++) {
      int r = wm * 64 + i * 16 + lr;
      afh[i] = *(const bf16x8*)&As[0][r][lk * 8];
      afl[i] = *(const bf16x8*)&As[1][r][lk * 8];
    }
    #pragma unroll
    for (int j = 0; j < 2; j++) {
      int r = wn * 32 + j * 16 + lr;
      wfh[j] = *(const bf16x8*)&Ws[0][r][lk * 8];
      wfl[j] = *(const bf16x8*)&Ws[1][r][lk * 8];
    }
    #pragma unroll
    for (int i = 0; i < 4; i++)
      #pragma unroll
      for (int j = 0; j < 2; j++) {
        acc[i][j] = __builtin_amdgcn_mfma_f32_16x16x32_bf16(afh[i], wfh[j], acc[i][j], 0, 0, 0);
        acc[i][j] = __builtin_amdgcn_mfma_f32_16x16x32_bf16(afh[i], wfl[j], acc[i][j], 0, 0, 0);
        acc[i][j] = __builtin_amdgcn_mfma_f32_16x16x32_bf16(afl[i], wfh[j], acc[i][j], 0, 0, 0);
      }
    __syncthreads();
  }

  #pragma unroll
  for (int i = 0; i < 4; i++)
    #pragma unroll
    for (int j = 0; j < 2; j++) {
      int col = bn0 + wn * 32 + j * 16 + lr;
      if (col < N) {
        float bv = BIAS ? bias[col] : 0.f;
        #pragma unroll
        for (int rr = 0; rr < 4; rr++) {
          int row = bm0 + wm * 64 + i * 16 + lk * 4 + rr;
          float v = acc[i][j][rr] + bv;
          size_t o = (size_t)row * N + col;
          if constexpr (FOUT) C[o] = v;
          if constexpr (SPLITOUT) {
            u16 hb = f2bf(v);
            Chi[o] = hb;
            Clo[o] = f2bf(v - bf2f(hb));
          }
        }
      }
    }
}

// depthwise causal conv K=4, + bias + silu; outputs split bf16 xc
__global__ __launch_bounds__(256) void conv_silu_kernel(
    const float* __restrict__ xz,
    const float* __restrict__ convw,
    const float* __restrict__ convb,
    u16* __restrict__ xch, u16* __restrict__ xcl)
{
  int idx = blockIdx.x * 256 + threadIdx.x;
  int d = idx & 511;
  int l = (idx >> 9) & 511;
  int b = idx >> 18;
  float acc = convb[d];
  #pragma unroll
  for (int k = 0; k < 4; k++) {
    int ll = l - 3 + k;
    if (ll >= 0) acc += convw[d * 4 + k] * xz[((size_t)(b * 512 + ll)) * 1024 + d];
  }
  float v = silu_f(acc);
  u16 hb = f2bf(v);
  xch[idx] = hb;
  xcl[idx] = f2bf(v - bf2f(hb));
}

// ---------------- chunked scan, register-state form ----------------
// ps/hs layout: [c:16][b:16][n:16][d:512]; thread = (b,d), 16 n-states in regs.

__global__ __launch_bounds__(256) void scan_part1(
    const u16* __restrict__ xch, const u16* __restrict__ xcl,
    const float* __restrict__ dbl,
    const float* __restrict__ Wdt, const float* __restrict__ bdt,
    const float* __restrict__ Alog,
    float2* __restrict__ ps)
{
  int bx = blockIdx.x;
  int c = bx & 15, b = (bx >> 4) & 15, dg = bx >> 8;
  int d = dg * 256 + threadIdx.x;
  int t0 = c * 32;

  float wdt[16], A[16];
  #pragma unroll
  for (int q = 0; q < 4; q++) {
    float4 w4 = *(const float4*)(Wdt + d * 16 + q * 4);
    wdt[q * 4 + 0] = w4.x; wdt[q * 4 + 1] = w4.y; wdt[q * 4 + 2] = w4.z; wdt[q * 4 + 3] = w4.w;
    float4 a4 = *(const float4*)(Alog + d * 16 + q * 4);
    A[q * 4 + 0] = -__expf(a4.x); A[q * 4 + 1] = -__expf(a4.y);
    A[q * 4 + 2] = -__expf(a4.z); A[q * 4 + 3] = -__expf(a4.w);
  }
  float bdtv = bdt[d];
  float S[16], P[16];
  #pragma unroll
  for (int n = 0; n < 16; n++) { S[n] = 0.f; P[n] = 1.f; }

  const float* dblb = dbl + (size_t)(b * 512 + t0) * 48;  // wave-uniform
  const u16* uph = xch + (size_t)(b * 512 + t0) * 512 + d;
  const u16* upl = xcl + (size_t)(b * 512 + t0) * 512 + d;

  for (int t = 0; t < 32; t++) {
    const float* dr = dblb + t * 48;
    float dtv = bdtv;
    #pragma unroll
    for (int q = 0; q < 4; q++) {
      float4 r4 = *(const float4*)(dr + q * 4);
      dtv += r4.x * wdt[q * 4 + 0] + r4.y * wdt[q * 4 + 1]
           + r4.z * wdt[q * 4 + 2] + r4.w * wdt[q * 4 + 3];
    }
    dtv = softplus_f(dtv);
    float u = bf2f(uph[t * 512]) + bf2f(upl[t * 512]);
    float w = dtv * u;
    #pragma unroll
    for (int q = 0; q < 4; q++) {
      float4 B4 = *(const float4*)(dr + 16 + q * 4);
      float Bj[4] = {B4.x, B4.y, B4.z, B4.w};
      #pragma unroll
      for (int j = 0; j < 4; j++) {
        int n = q * 4 + j;
        float a = __expf(dtv * A[n]);
        S[n] = a * S[n] + w * Bj[j];
        P[n] *= a;
      }
    }
  }
  float2* pp = ps + ((size_t)(c * 16 + b) * 16) * 512 + d;
  #pragma unroll
  for (int n = 0; n < 16; n++) pp[(size_t)n * 512] = make_float2(P[n], S[n]);
}

__global__ __launch_bounds__(256) void scan_part2(
    const float2* __restrict__ ps, float* __restrict__ hs)
{
  int idx = blockIdx.x * 256 + threadIdx.x; // 131072 = (b,n,d)
  float h = 0.f;
  #pragma unroll
  for (int c = 0; c < 16; c++) {
    float2 v = ps[(size_t)c * 131072 + idx];
    hs[(size_t)c * 131072 + idx] = h;
    h = v.x * h + v.y;
  }
}

__global__ __launch_bounds__(256) void scan_part3(
    const u16* __restrict__ xch, const u16* __restrict__ xcl,
    const float* __restrict__ dbl,
    const float* __restrict__ xz,   // z at col 512
    const float* __restrict__ Wdt, const float* __restrict__ bdt,
    const float* __restrict__ Alog, const float* __restrict__ Dp,
    const float* __restrict__ hs,
    u16* __restrict__ yh, u16* __restrict__ yl)
{
  int bx = blockIdx.x;
  int c = bx & 15, b = (bx >> 4) & 15, dg = bx >> 8;
  int d = dg * 256 + threadIdx.x;
  int t0 = c * 32;

  float wdt[16], A[16];
  #pragma unroll
  for (int q = 0; q < 4; q++) {
    float4 w4 = *(const float4*)(Wdt + d * 16 + q * 4);
    wdt[q * 4 + 0] = w4.x; wdt[q * 4 + 1] = w4.y; wdt[q * 4 + 2] = w4.z; wdt[q * 4 + 3] = w4.w;
    float4 a4 = *(const float4*)(Alog + d * 16 + q * 4);
    A[q * 4 + 0] = -__expf(a4.x); A[q * 4 + 1] = -__expf(a4.y);
    A[q * 4 + 2] = -__expf(a4.z); A[q * 4 + 3] = -__expf(a4.w);
  }
  float bdtv = bdt[d];
  float Dv = Dp[d];
  float h[16];
  {
    const float* hp = hs + ((size_t)(c * 16 + b) * 16) * 512 + d;
    #pragma unroll
    for (int n = 0; n < 16; n++) h[n] = hp[(size_t)n * 512];
  }

  const float* dblb = dbl + (size_t)(b * 512 + t0) * 48;  // wave-uniform
  const u16* uph = xch + (size_t)(b * 512 + t0) * 512 + d;
  const u16* upl = xcl + (size_t)(b * 512 + t0) * 512 + d;
  const float* zp = xz + (size_t)(b * 512 + t0) * 1024 + 512 + d;
  u16* yhp = yh + (size_t)(b * 512 + t0) * 512 + d;
  u16* ylp = yl + (size_t)(b * 512 + t0) * 512 + d;

  for (int t = 0; t < 32; t++) {
    const float* dr = dblb + t * 48;
    float dtv = bdtv;
    #pragma unroll
    for (int q = 0; q < 4; q++) {
      float4 r4 = *(const float4*)(dr + q * 4);
      dtv += r4.x * wdt[q * 4 + 0] + r4.y * wdt[q * 4 + 1]
           + r4.z * wdt[q * 4 + 2] + r4.w * wdt[q * 4 + 3];
    }
    dtv = softplus_f(dtv);
    float u = bf2f(uph[t * 512]) + bf2f(upl[t * 512]);
    float w = dtv * u;
    float y = 0.f;
    #pragma unroll
    for (int q = 0; q < 4; q++) {
      float4 B4 = *(const float4*)(dr + 16 + q * 4);
      float4 C4 = *(const float4*)(dr + 32 + q * 4);
      float Bj[4] = {B4.x, B4.y, B4.z, B4.w};
      float Cj[4] = {C4.x, C4.y, C4.z, C4.w};
      #pragma unroll
      for (int j = 0; j < 4; j++) {
        int n = q * 4 + j;
        float a = __expf(dtv * A[n]);
        h[n] = a * h[n] + w * Bj[j];
        y += h[n] * Cj[j];
      }
    }
    float zv = zp[t * 1024];
    float v = (y + u * Dv) * silu_f(zv);
    u16 hb = f2bf(v);
    yhp[t * 512] = hb;
    ylp[t * 512] = f2bf(v - bf2f(hb));
  }
}

__global__ void pool_kernel(const float* __restrict__ h, float* __restrict__ pooled) {
  int b = blockIdx.x, d = threadIdx.x;
  float s = 0.f;
  for (int l = 0; l < 512; l++) s += h[((size_t)(b * 512 + l)) * 256 + d];
  pooled[b * 256 + d] = s * (1.f / 512.f);
}

__global__ void small_gemm_kernel(const float* __restrict__ A, const float* __restrict__ W,
                                  const float* __restrict__ bias, float* __restrict__ C,
                                  int Mb, int N, int K) {
  int idx = blockIdx.x * blockDim.x + threadIdx.x;
  if (idx >= Mb * N) return;
  int b = idx / N, n = idx - b * N;
  float acc = bias[n];
  for (int k = 0; k < K; k++) acc += A[b * K + k] * W[n * K + k];
  C[idx] = acc;
}

__global__ void bcast_kernel(const float* __restrict__ s, u16* __restrict__ hh, u16* __restrict__ hl) {
  int idx = blockIdx.x * 256 + threadIdx.x; // over 8192*256
  int d = idx & 255;
  int b = idx >> 17;
  float v = s[b * 256 + d];
  u16 hb = f2bf(v);
  hh[idx] = hb;
  hl[idx] = f2bf(v - bf2f(hb));
}

extern "C" void kernel_launch(void* const* d_in, const int* in_sizes, int n_in,
                              void* d_out, int out_size, void* d_ws, size_t ws_size,
                              hipStream_t stream) {
  const float* x     = (const float*)d_in[0];
  const float* emb_W = (const float*)d_in[1];
  const float* emb_b = (const float*)d_in[2];
  const float* lat_W = (const float*)d_in[3];
  const float* lat_b = (const float*)d_in[4];
  const float* l2s_W = (const float*)d_in[5];
  const float* l2s_b = (const float*)d_in[6];
  const float* out_W = (const float*)d_in[7];
  const float* out_b = (const float*)d_in[8];

  char* base = (char*)d_ws;
  float*  h      = (float*) (base + 0);          //  8,388,608 B
  float*  xz     = (float*) (base + 8388608);    // 33,554,432
  float*  dbl    = (float*) (base + 41943040);   //  1,572,864
  float2* ps     = (float2*)(base + 43515904);   // 16,777,216
  float*  hs     = (float*) (base + 60293120);   //  8,388,608
  u16*    h_hi   = (u16*)   (base + 68681728);   //  4,194,304
  u16*    h_lo   = (u16*)   (base + 72876032);   //  4,194,304
  u16*    xc_hi  = (u16*)   (base + 77070336);   //  8,388,608
  u16*    xc_lo  = (u16*)   (base + 85458944);   //  8,388,608
  u16*    x_hi   = (u16*)   (base + 93847552);   //  1,048,576
  u16*    x_lo   = (u16*)   (base + 94896128);   //  1,048,576
  u16*    w_hi   = (u16*)   (base + 95944704);   //  3,407,872
  u16*    w_lo   = (u16*)   (base + 99352576);   //  3,407,872
  float*  pooled = (float*) (base + 102760448);  //     16,384
  float*  s_sml  = (float*) (base + 102776832);  //     16,384
  // y split aliases ps (ps dead once scan_part2 consumed it; Wout runs before next part1)
  u16* y_hi = (u16*)ps;
  u16* y_lo = (u16*)((char*)ps + 8388608);

  float* recon  = (float*)d_out;      // 8192*64
  float* latent = recon + 524288;     // 16*128

  dim3 blk(256);

  // ---- split pre-pass: x + all GEMM weights ----
  SplitList sl;
  const float* srcs[9] = {x, emb_W, out_W,
                          (const float*)d_in[9],  (const float*)d_in[12], (const float*)d_in[17],
                          (const float*)d_in[18], (const float*)d_in[21], (const float*)d_in[26]};
  size_t offs[9] = {0, 0, 16384, 32768, 557056, 606208, 868352, 1392640, 1441792};
  int    n4s[9]  = {131072, 4096, 4096, 131072, 12288, 65536, 131072, 12288, 65536};
  for (int t = 0; t < 9; t++) {
    sl.src[t] = srcs[t];
    sl.hi[t] = (t == 0) ? x_hi : w_hi + offs[t];
    sl.lo[t] = (t == 0) ? x_lo : w_lo + offs[t];
    sl.n4[t] = n4s[t];
  }
  int total4 = 557056;
  hipLaunchKernelGGL(split_kernel, dim3(total4 / 256), blk, 0, stream, sl, total4);

  // h = x @ emb_W.T + emb_b  (split out only)
  hipLaunchKernelGGL((gemm_mfma<true, false, true>), dim3(4, 64), blk, 0, stream,
                     x_hi, x_lo, 64, w_hi + 0, w_lo + 0, emb_b,
                     nullptr, h_hi, h_lo, MROWS, 256, 64);

  auto run_layer = [&](int base_in, size_t wpre, int i, bool foutH) {
    const float* cw   = (const float*)d_in[base_in + 1] + (size_t)i * 512 * 4;
    const float* cb   = (const float*)d_in[base_in + 2] + (size_t)i * 512;
    const float* Wdt  = (const float*)d_in[base_in + 4] + (size_t)i * 512 * 16;
    const float* bdt  = (const float*)d_in[base_in + 5] + (size_t)i * 512;
    const float* Alog = (const float*)d_in[base_in + 6] + (size_t)i * 512 * 16;
    const float* Dpp  = (const float*)d_in[base_in + 7] + (size_t)i * 512;
    const u16* WinH  = w_hi + wpre + (size_t)i * 262144;
    const u16* WinL  = w_lo + wpre + (size_t)i * 262144;
    const u16* WxH   = w_hi + wpre + 524288 + (size_t)i * 24576;
    const u16* WxL   = w_lo + wpre + 524288 + (size_t)i * 24576;
    const u16* WoutH = w_hi + wpre + 573440 + (size_t)i * 131072;
    const u16* WoutL = w_lo + wpre + 573440 + (size_t)i * 131072;

    // xz = h @ Win.T
    hipLaunchKernelGGL((gemm_mfma<false, true, false>), dim3(16, 64), blk, 0, stream,
                       h_hi, h_lo, 256, WinH, WinL, nullptr, xz, nullptr, nullptr, MROWS, 1024, 256);
    // xc = silu(conv(xz[:, :512]) + cb) -> split
    hipLaunchKernelGGL(conv_silu_kernel, dim3(MROWS * 512 / 256), blk, 0, stream,
                       xz, cw, cb, xc_hi, xc_lo);
    // dbl = xc @ Wx.T (N=48)
    hipLaunchKernelGGL((gemm_mfma<false, true, false>), dim3(1, 64), blk, 0, stream,
                       xc_hi, xc_lo, 512, WxH, WxL, nullptr, dbl, nullptr, nullptr, MROWS, 48, 512);
    // chunked scan (dt fused, register-state)
    hipLaunchKernelGGL(scan_part1, dim3(512), blk, 0, stream,
                       xc_hi, xc_lo, dbl, Wdt, bdt, Alog, ps);
    hipLaunchKernelGGL(scan_part2, dim3(131072 / 256), blk, 0, stream,
                       (const float2*)ps, hs);
    hipLaunchKernelGGL(scan_part3, dim3(512), blk, 0, stream,
                       xc_hi, xc_lo, dbl, xz, Wdt, bdt, Alog, Dpp, hs, y_hi, y_lo);
    // h = y @ Wout.T
    if (foutH)
      hipLaunchKernelGGL((gemm_mfma<false, true, true>), dim3(4, 64), blk, 0, stream,
                         y_hi, y_lo, 512, WoutH, WoutL, nullptr, h, h_hi, h_lo, MROWS, 256, 512);
    else
      hipLaunchKernelGGL((gemm_mfma<false, false, true>), dim3(4, 64), blk, 0, stream,
                         y_hi, y_lo, 512, WoutH, WoutL, nullptr, nullptr, h_hi, h_lo, MROWS, 256, 512);
  };

  run_layer(9, 32768, 0, false);
  run_layer(9, 32768, 1, true);   // pool needs f32 h

  hipLaunchKernelGGL(pool_kernel, dim3(16), blk, 0, stream, h, pooled);
  hipLaunchKernelGGL(small_gemm_kernel, dim3((16 * 128 + 255) / 256), blk, 0, stream,
                     pooled, lat_W, lat_b, latent, 16, 128, 256);
  hipLaunchKernelGGL(small_gemm_kernel, dim3((16 * 256 + 255) / 256), blk, 0, stream,
                     latent, l2s_W, l2s_b, s_sml, 16, 256, 128);
  hipLaunchKernelGGL(bcast_kernel, dim3(8192 * 256 / 256), blk, 0, stream, s_sml, h_hi, h_lo);

  run_layer(18, 868352, 0, false);
  run_layer(18, 868352, 1, false);

  // recon = h @ out_W.T + out_b
  hipLaunchKernelGGL((gemm_mfma<true, true, false>), dim3(1, 64), blk, 0, stream,
                     h_hi, h_lo, 256, w_hi + 16384, w_lo + 16384, out_b,
                     recon, nullptr, nullptr, MROWS, 64, 256);
}